// Round 14
// baseline (64.225 us; speedup 1.0000x reference)
//
#include <hip/hip_runtime.h>
#include <math.h>

#define HIDDEN 128
#define NGRAPH 16384
#define GPB 32                  // graphs per block
#define NBLK (NGRAPH / GPB)     // 512 blocks
#define NTHR 256                // 4 waves/block; 2 blocks/CU = 8 waves/CU

typedef __attribute__((ext_vector_type(8))) short short8;   // 8 bf16
typedef __attribute__((ext_vector_type(4))) float f32x4;    // MFMA accum

// shifted-softplus shift = log(2)
__device__ __constant__ float kSHIFT = 0.69314718055994530942f;

// fp32 -> bf16 (RNE), bit-level
__device__ __forceinline__ unsigned short f2bf(float f) {
    unsigned int u = __builtin_bit_cast(unsigned int, f);
    u = (u + 0x7FFFu + ((u >> 16) & 1u)) >> 16;
    return (unsigned short)u;
}

// ---------------------------------------------------------------------------
// Kernel 0: boundary scan. batch sorted; thread i writes offs[g]=i for every
// graph g starting at i (covers empty graphs). offs[NGRAPH]=n_nodes.
// (R9/R12: computing offsets inside the fused kernel costs >= this kernel.)
// ---------------------------------------------------------------------------
__global__ __launch_bounds__(256) void offsets_kernel(
    const int* __restrict__ batch, int* __restrict__ offs, int n_nodes)
{
    int i = blockIdx.x * blockDim.x + threadIdx.x;
    if (i >= n_nodes) return;
    int b = batch[i];
    int prev = (i == 0) ? -1 : batch[i - 1];
    for (int g = prev + 1; g <= b; ++g) offs[g] = i;        // rare
    if (i == n_nodes - 1)
        for (int g = b + 1; g <= NGRAPH; ++g) offs[g] = n_nodes;
}

// ---------------------------------------------------------------------------
// Fused kernel: 512 blocks x 256 threads (4 waves), 32 graphs/block.
// Phase 1 (R6's structure -- the fastest measured streaming): each wave
//   streams the contiguous rows of its EIGHT graphs (~244-row streams; R6/R8
//   A/B showed 2048x244-row streams beat 4096x122-row by ~9 us). 64 lanes
//   cover a row as float2; 8 rows per straight-line block (8 loads in
//   flight/lane); wave-uniform boundary flush packs the fp32 run to bf16 and
//   stores it XOR-swizzled into u_b (direct store, no shfl, no atomics).
// Phase 2 (R8's MFMA, re-partitioned for 4 waves): wave w owns W1 cols
//   [w*64,(w+1)*64) as register B-frags bfrag[4][4] (loaded once, before
//   phase 1, latency hidden); 32 x v_mfma_f32_16x16x32_bf16 per wave with
//   conflict-free swizzled ds_read_b128 A-frags. Epilogue: bias -> shifted
//   softplus -> *W2 -> 16-lane shfl reduce -> 4-wave LDS reduce.
// LDS: 8 KB u_b + 0.5 KB red + 132 B offs. VGPR ~150 -> 2 waves/SIMD ok.
// ---------------------------------------------------------------------------
__global__ __launch_bounds__(NTHR, 2) void fused_kernel(
    const float* __restrict__ v, const int* __restrict__ offs,
    const float* __restrict__ W1, const float* __restrict__ b1,
    const float* __restrict__ W2, const float* __restrict__ b2,
    float* __restrict__ out)
{
    __shared__ short u_b[GPB * HIDDEN];    // 8 KB, bf16, k XOR-swizzled per row
    __shared__ float red_s[4][GPB];        // 0.5 KB
    __shared__ int   offs_s[GPB + 1];

    const int t  = threadIdx.x;
    const int l  = t & 63;
    const int w  = t >> 6;                 // wave id 0..3
    const int g0 = blockIdx.x * GPB;
    const int w8 = w * 8;                  // this wave's first local graph

    if (t < GPB + 1) offs_s[t] = offs[g0 + t];

    // ---- B-fragments: W1 cols [w*64, w*64+64), bf16, registers ----
    // frag[ct][kt]: lane l holds B[k = kt*32+(l>>4)*8+j][col = w*64+ct*16+(l&15)]
    short8 bfrag[4][4];
    {
        const int lcol = w * 64 + (l & 15);
        #pragma unroll
        for (int ct = 0; ct < 4; ++ct) {
            const int col = lcol + ct * 16;
            #pragma unroll
            for (int kt = 0; kt < 4; ++kt) {
                const int k0 = kt * 32 + (l >> 4) * 8;
                short8 f;
                #pragma unroll
                for (int j = 0; j < 8; ++j)
                    f[j] = (short)f2bf(W1[(size_t)(k0 + j) * 256 + col]);
                bfrag[ct][kt] = f;
            }
        }
    }
    __syncthreads();   // offs_s ready

    // ---------------- Phase 1: continuous segment-sum stream ----------------
    const float2* __restrict__ v2 = reinterpret_cast<const float2*>(v);
    const int lo = offs_s[w8];
    const int hi = offs_s[w8 + 8];
    int cur = 0;
    int bnd = offs_s[w8 + 1];
    float accx = 0.f, accy = 0.f;
    const int k2 = 2 * l;                  // lane's k-pair base

    for (int r = lo; r < hi; r += 8) {
        // straight-line load block: 8 float2 loads in flight per lane
        float2 x[8];
        #pragma unroll
        for (int q = 0; q < 8; ++q) {
            int rq = r + q;
            rq = (rq < hi) ? rq : (hi - 1);          // clamp tail (uniform)
            x[q] = v2[(size_t)rq * 64 + l];
        }
        // accumulate with rare wave-uniform boundary flushes
        #pragma unroll
        for (int q = 0; q < 8; ++q) {
            if (r + q < hi) {
                while (r + q >= bnd) {               // taken ~1 in 30 rows
                    const int row = w8 + cur;
                    const int idx = row * HIDDEN + (k2 ^ ((row & 7) * 8));
                    unsigned int pk = (unsigned int)f2bf(accx)
                                    | ((unsigned int)f2bf(accy) << 16);
                    *reinterpret_cast<unsigned int*>(&u_b[idx]) = pk;
                    accx = 0.f; accy = 0.f;
                    ++cur;
                    bnd = offs_s[w8 + cur + 1];      // index <= 32
                }
                accx += x[q].x; accy += x[q].y;
            }
        }
    }
    while (cur < 8) {                                 // flush last + empties
        const int row = w8 + cur;
        const int idx = row * HIDDEN + (k2 ^ ((row & 7) * 8));
        unsigned int pk = (unsigned int)f2bf(accx)
                        | ((unsigned int)f2bf(accy) << 16);
        *reinterpret_cast<unsigned int*>(&u_b[idx]) = pk;
        accx = 0.f; accy = 0.f;
        ++cur;
    }
    __syncthreads();

    // ---------------- Phase 2: MFMA MLP ----------------
    f32x4 acc[2][4];                       // [row-tile][col-tile]
    #pragma unroll
    for (int rt = 0; rt < 2; ++rt)
        #pragma unroll
        for (int ct = 0; ct < 4; ++ct)
            acc[rt][ct] = (f32x4){0.f, 0.f, 0.f, 0.f};

    #pragma unroll
    for (int kt = 0; kt < 4; ++kt) {
        #pragma unroll
        for (int rt = 0; rt < 2; ++rt) {
            const int row = rt * 16 + (l & 15);
            const int k0  = kt * 32 + (l >> 4) * 8;
            short8 a = *reinterpret_cast<const short8*>(
                &u_b[row * HIDDEN + (k0 ^ ((row & 7) * 8))]);
            #pragma unroll
            for (int ct = 0; ct < 4; ++ct)
                acc[rt][ct] = __builtin_amdgcn_mfma_f32_16x16x32_bf16(
                    a, bfrag[ct][kt], acc[rt][ct], 0, 0, 0);
        }
    }

    // epilogue: bias -> shifted softplus -> *W2 -> reduce 16 cols -> LDS
    float b1c[4], w2c[4];
    #pragma unroll
    for (int ct = 0; ct < 4; ++ct) {
        const int col = w * 64 + ct * 16 + (l & 15);
        b1c[ct] = b1[col];
        w2c[ct] = W2[col];
    }
    #pragma unroll
    for (int rt = 0; rt < 2; ++rt) {
        float p[4] = {0.f, 0.f, 0.f, 0.f};
        #pragma unroll
        for (int ct = 0; ct < 4; ++ct)
            #pragma unroll
            for (int reg = 0; reg < 4; ++reg) {
                float x = acc[rt][ct][reg] + b1c[ct];
                float h = fmaxf(x, 0.f) + log1pf(expf(-fabsf(x))) - kSHIFT;
                p[reg] = fmaf(h, w2c[ct], p[reg]);
            }
        #pragma unroll
        for (int reg = 0; reg < 4; ++reg) {
            float s = p[reg];
            s += __shfl_xor(s, 1);
            s += __shfl_xor(s, 2);
            s += __shfl_xor(s, 4);
            s += __shfl_xor(s, 8);
            if ((l & 15) == 0)
                red_s[w][rt * 16 + (l >> 4) * 4 + reg] = s;
        }
    }
    __syncthreads();

    if (t < GPB) {
        float s = (red_s[0][t] + red_s[1][t]) + (red_s[2][t] + red_s[3][t]);
        out[g0 + t] = s + b2[0];
    }
}

extern "C" void kernel_launch(void* const* d_in, const int* in_sizes, int n_in,
                              void* d_out, int out_size, void* d_ws, size_t ws_size,
                              hipStream_t stream) {
    const float* v     = (const float*)d_in[0];
    const int*   batch = (const int*)d_in[1];
    const float* W1    = (const float*)d_in[2];
    const float* b1    = (const float*)d_in[3];
    const float* W2    = (const float*)d_in[4];
    const float* b2    = (const float*)d_in[5];
    float* out = (float*)d_out;

    const int n_nodes = in_sizes[0] / HIDDEN;   // 500000
    int* offs = (int*)d_ws;                     // (NGRAPH+1) ints

    offsets_kernel<<<(n_nodes + 255) / 256, 256, 0, stream>>>(batch, offs, n_nodes);
    fused_kernel<<<NBLK, NTHR, 0, stream>>>(v, offs, W1, b1, W2, b2, out);
}

// Round 16
// 63.937 us; speedup vs baseline: 1.0045x; 1.0045x over previous
//
#include <hip/hip_runtime.h>
#include <math.h>

#define HIDDEN 128
#define NGRAPH 16384
#define GPB 32                  // graphs per block
#define NBLK (NGRAPH / GPB)     // 512 blocks
#define NTHR 512                // 8 waves/block; 2 blocks/CU = 16 waves/CU

typedef __attribute__((ext_vector_type(8))) short short8;   // 8 bf16
typedef __attribute__((ext_vector_type(4))) float f32x4;    // MFMA accum
typedef __attribute__((ext_vector_type(2))) float f32x2;    // nt-load-able float2

// shifted-softplus shift = log(2)
__device__ __constant__ float kSHIFT = 0.69314718055994530942f;

// fp32 -> bf16 (RNE), bit-level
__device__ __forceinline__ unsigned short f2bf(float f) {
    unsigned int u = __builtin_bit_cast(unsigned int, f);
    u = (u + 0x7FFFu + ((u >> 16) & 1u)) >> 16;
    return (unsigned short)u;
}

// ---------------------------------------------------------------------------
// Kernel 0: boundary scan. batch sorted; thread i writes offs[g]=i for every
// graph g starting at i (covers empty graphs). offs[NGRAPH]=n_nodes.
// (R9/R12: in-kernel offset computation costs >= this kernel. Keep it.)
// ---------------------------------------------------------------------------
__global__ __launch_bounds__(256) void offsets_kernel(
    const int* __restrict__ batch, int* __restrict__ offs, int n_nodes)
{
    int i = blockIdx.x * blockDim.x + threadIdx.x;
    if (i >= n_nodes) return;
    int b = batch[i];
    int prev = (i == 0) ? -1 : batch[i - 1];
    for (int g = prev + 1; g <= b; ++g) offs[g] = i;        // rare
    if (i == n_nodes - 1)
        for (int g = b + 1; g <= NGRAPH; ++g) offs[g] = n_nodes;
}

// ---------------------------------------------------------------------------
// Fused kernel == ROUND-8 BASELINE (best: 60.3 us) + ONE CHANGE:
//   v loads are NON-TEMPORAL (f32x2 ext-vector, which the builtin accepts).
//   v has zero intra-pass reuse; the mixed L3-hit/HBM-miss stream ran at
//   only ~5.0 TB/s effective. nt loads make phase 1 a pure HBM stream
//   (hypothesis: ~6.5-7 TB/s like the fills).
// Everything else identical to R8: 8 waves x 4 graphs, float2 lanes,
// 8-row straight-line load blocks, wave-uniform bf16-swizzled LDS flush,
// register B-frags, 16 MFMA phase 2, shfl+LDS reduce epilogue.
// ---------------------------------------------------------------------------
__global__ __launch_bounds__(NTHR, 4) void fused_kernel(
    const float* __restrict__ v, const int* __restrict__ offs,
    const float* __restrict__ W1, const float* __restrict__ b1,
    const float* __restrict__ W2, const float* __restrict__ b2,
    float* __restrict__ out)
{
    __shared__ short u_b[GPB * HIDDEN];    // 8 KB, bf16, k XOR-swizzled per row
    __shared__ float red_s[8][GPB];        // 1 KB
    __shared__ int   offs_s[GPB + 1];

    const int t  = threadIdx.x;
    const int l  = t & 63;
    const int w  = t >> 6;                 // wave id 0..7
    const int g0 = blockIdx.x * GPB;
    const int w4 = w * 4;                  // this wave's first local graph

    if (t < GPB + 1) offs_s[t] = offs[g0 + t];

    // ---- B-fragments: W1 cols [w*32, w*32+32), bf16, registers ----
    // frag[ct][kt]: lane l holds B[k = kt*32+(l>>4)*8+j][col = w*32+ct*16+(l&15)]
    short8 bfrag[2][4];
    {
        const int lcol = w * 32 + (l & 15);
        #pragma unroll
        for (int ct = 0; ct < 2; ++ct) {
            const int col = lcol + ct * 16;
            #pragma unroll
            for (int kt = 0; kt < 4; ++kt) {
                const int k0 = kt * 32 + (l >> 4) * 8;
                short8 f;
                #pragma unroll
                for (int j = 0; j < 8; ++j)
                    f[j] = (short)f2bf(W1[(size_t)(k0 + j) * 256 + col]);
                bfrag[ct][kt] = f;
            }
        }
    }
    __syncthreads();   // offs_s ready

    // ---------------- Phase 1: continuous segment-sum stream ----------------
    const f32x2* __restrict__ v2 = reinterpret_cast<const f32x2*>(v);
    const int lo = offs_s[w4];
    const int hi = offs_s[w4 + 4];
    int cur = 0;
    int bnd = offs_s[w4 + 1];
    float accx = 0.f, accy = 0.f;
    const int k2 = 2 * l;                  // lane's k-pair base

    for (int r = lo; r < hi; r += 8) {
        f32x2 x[8];
        #pragma unroll
        for (int q = 0; q < 8; ++q) {
            int rq = r + q;
            rq = (rq < hi) ? rq : (hi - 1);          // clamp tail (uniform)
            x[q] = __builtin_nontemporal_load(&v2[(size_t)rq * 64 + l]);
        }
        #pragma unroll
        for (int q = 0; q < 8; ++q) {
            if (r + q < hi) {
                while (r + q >= bnd) {               // taken ~1 in 30 rows
                    const int row = w4 + cur;
                    const int idx = row * HIDDEN + (k2 ^ ((row & 7) * 8));
                    unsigned int pk = (unsigned int)f2bf(accx)
                                    | ((unsigned int)f2bf(accy) << 16);
                    *reinterpret_cast<unsigned int*>(&u_b[idx]) = pk;
                    accx = 0.f; accy = 0.f;
                    ++cur;
                    bnd = offs_s[w4 + cur + 1];      // index <= 32
                }
                accx += x[q][0]; accy += x[q][1];
            }
        }
    }
    while (cur < 4) {                                 // flush last + empties
        const int row = w4 + cur;
        const int idx = row * HIDDEN + (k2 ^ ((row & 7) * 8));
        unsigned int pk = (unsigned int)f2bf(accx)
                        | ((unsigned int)f2bf(accy) << 16);
        *reinterpret_cast<unsigned int*>(&u_b[idx]) = pk;
        accx = 0.f; accy = 0.f;
        ++cur;
    }
    __syncthreads();

    // ---------------- Phase 2: MFMA MLP ----------------
    f32x4 acc[2][2];                       // [row-tile][col-tile]
    #pragma unroll
    for (int rt = 0; rt < 2; ++rt)
        #pragma unroll
        for (int ct = 0; ct < 2; ++ct)
            acc[rt][ct] = (f32x4){0.f, 0.f, 0.f, 0.f};

    #pragma unroll
    for (int kt = 0; kt < 4; ++kt) {
        #pragma unroll
        for (int rt = 0; rt < 2; ++rt) {
            const int row = rt * 16 + (l & 15);
            const int k0  = kt * 32 + (l >> 4) * 8;
            short8 a = *reinterpret_cast<const short8*>(
                &u_b[row * HIDDEN + (k0 ^ ((row & 7) * 8))]);
            #pragma unroll
            for (int ct = 0; ct < 2; ++ct)
                acc[rt][ct] = __builtin_amdgcn_mfma_f32_16x16x32_bf16(
                    a, bfrag[ct][kt], acc[rt][ct], 0, 0, 0);
        }
    }

    // epilogue: bias -> shifted softplus -> *W2 -> reduce 16 cols -> LDS
    float b1c[2], w2c[2];
    #pragma unroll
    for (int ct = 0; ct < 2; ++ct) {
        const int col = w * 32 + ct * 16 + (l & 15);
        b1c[ct] = b1[col];
        w2c[ct] = W2[col];
    }
    #pragma unroll
    for (int rt = 0; rt < 2; ++rt) {
        float p[4] = {0.f, 0.f, 0.f, 0.f};
        #pragma unroll
        for (int ct = 0; ct < 2; ++ct)
            #pragma unroll
            for (int reg = 0; reg < 4; ++reg) {
                float x = acc[rt][ct][reg] + b1c[ct];
                float h = fmaxf(x, 0.f) + log1pf(expf(-fabsf(x))) - kSHIFT;
                p[reg] = fmaf(h, w2c[ct], p[reg]);
            }
        #pragma unroll
        for (int reg = 0; reg < 4; ++reg) {
            float s = p[reg];
            s += __shfl_xor(s, 1);
            s += __shfl_xor(s, 2);
            s += __shfl_xor(s, 4);
            s += __shfl_xor(s, 8);
            if ((l & 15) == 0)
                red_s[w][rt * 16 + (l >> 4) * 4 + reg] = s;
        }
    }
    __syncthreads();

    if (t < GPB) {
        float s = (red_s[0][t] + red_s[1][t]) + (red_s[2][t] + red_s[3][t])
                + (red_s[4][t] + red_s[5][t]) + (red_s[6][t] + red_s[7][t]);
        out[g0 + t] = s + b2[0];
    }
}

extern "C" void kernel_launch(void* const* d_in, const int* in_sizes, int n_in,
                              void* d_out, int out_size, void* d_ws, size_t ws_size,
                              hipStream_t stream) {
    const float* v     = (const float*)d_in[0];
    const int*   batch = (const int*)d_in[1];
    const float* W1    = (const float*)d_in[2];
    const float* b1    = (const float*)d_in[3];
    const float* W2    = (const float*)d_in[4];
    const float* b2    = (const float*)d_in[5];
    float* out = (float*)d_out;

    const int n_nodes = in_sizes[0] / HIDDEN;   // 500000
    int* offs = (int*)d_ws;                     // (NGRAPH+1) ints

    offsets_kernel<<<(n_nodes + 255) / 256, 256, 0, stream>>>(batch, offs, n_nodes);
    fused_kernel<<<NBLK, NTHR, 0, stream>>>(v, offs, W1, b1, W2, b2, out);
}